// Round 1
// baseline (485.050 us; speedup 1.0000x reference)
//
#include <hip/hip_runtime.h>
#include <math.h>

#define BB 8
#define NCLS 16
#define NPIX 16384
#define CHN 256
#define MAXV 200
#define SORTN 2048

// ---------------- ws layout (bytes) ----------------
// 0     : double acc            (loss accumulator)
// 64    : int counts[128]
// 1024  : int plan[536]: [0]=n_view [1]=k [2]=P [3]=D,
//         chan[16]@+4, pimg[128]@+20, pcls[128]@+148, pmap[128]@+276, Lp[128]@+404
// 8192  : float pos_[128*16]
// 16384 : float posnorm[128]
// 32768 : float cert[8*16384]   (512 KB)  -> total 557056 B

__global__ __launch_bounds__(256) void k_hist(const int* __restrict__ predict,
                                              int* __restrict__ counts) {
    __shared__ int h[NCLS];
    int tid = threadIdx.x;
    if (tid < NCLS) h[tid] = 0;
    __syncthreads();
    int base = blockIdx.x * 256;          // 512 blocks, never straddles an image
    int b = base >> 14;
    int v = predict[base + tid];
    if (v >= 0 && v < NCLS) atomicAdd(&h[v], 1);
    __syncthreads();
    if (tid < NCLS && h[tid] > 0) atomicAdd(&counts[b * NCLS + tid], h[tid]);
}

__global__ void k_plan(const int* __restrict__ counts, int* __restrict__ plan) {
    // single thread; replicates _plan's integer logic (order: image-major, class ascending)
    int* chan = plan + 4;
    int* pimg = plan + 20;
    int* pcls = plan + 148;
    int* pmap = plan + 276;
    int* Lp   = plan + 404;
    int D = 0;
    for (int v = 0; v < NCLS; ++v) {          // classes_index: any occurrence, sorted
        int tot = 0;
        for (int b = 0; b < BB; ++b) tot += counts[b * NCLS + v];
        if (tot > 0) chan[D++] = v;
    }
    int nview = 0x7fffffff, P = 0;
    for (int b = 0; b < BB; ++b)
        for (int v = 0; v < NCLS; ++v) {
            int c = counts[b * NCLS + v];
            pmap[b * NCLS + v] = -1;
            if (c >= MAXV) {
                pmap[b * NCLS + v] = P;
                pimg[P] = b; pcls[P] = v; Lp[P] = c;
                if (c < nview) nview = c;
                ++P;
            }
        }
    plan[0] = nview; plan[1] = nview / 2; plan[2] = P; plan[3] = D;
}

// certainty = top1 - top2 over the 256 channels of each pixel (exactly lax.top_k(...,2))
__global__ __launch_bounds__(256) void k_cert(const float* __restrict__ feats,
                                              float* __restrict__ cert) {
    int t = blockIdx.x * 256 + threadIdx.x;   // 32768 threads, 4 pixels each
    int b = t >> 12;
    int n4 = (t & 4095) * 4;
    const float* fb = feats + (size_t)b * CHN * NPIX + n4;
    float m1[4] = {-INFINITY, -INFINITY, -INFINITY, -INFINITY};
    float m2[4] = {-INFINITY, -INFINITY, -INFINITY, -INFINITY};
    for (int c = 0; c < CHN; ++c) {
        const float4 x = *(const float4*)(fb + (size_t)c * NPIX);
        float xv[4] = {x.x, x.y, x.z, x.w};
#pragma unroll
        for (int q = 0; q < 4; ++q) {
            float val = xv[q];
            if (val > m1[q]) { m2[q] = m1[q]; m1[q] = val; }
            else if (val > m2[q]) m2[q] = val;
        }
    }
    float4 o = {m1[0] - m2[0], m1[1] - m2[1], m1[2] - m2[2], m1[3] - m2[3]};
    *(float4*)(cert + b * NPIX + n4) = o;
}

// one block per (b,v): collect class pixels, bitonic-sort by (certainty desc, pixel asc),
// average channels chan[0..D) over top-k pixels -> pos_[p]
__global__ __launch_bounds__(256) void k_topk(const float* __restrict__ feats,
                                              const int* __restrict__ predict,
                                              const float* __restrict__ cert,
                                              const int* __restrict__ plan,
                                              float* __restrict__ pos_) {
    __shared__ unsigned long long keys[SORTN];
    __shared__ int lcnt;
    __shared__ float red[256];
    int tid = threadIdx.x;
    int b = blockIdx.x >> 4, v = blockIdx.x & 15;
    const int* chan = plan + 4;
    const int* pmap = plan + 276;
    int p = pmap[b * NCLS + v];
    if (p < 0) return;
    int kwant = plan[1], D = plan[3];
    if (tid == 0) lcnt = 0;
    __syncthreads();
    for (int n = tid; n < NPIX; n += 256) {
        if (predict[b * NPIX + n] == v) {
            int pos = atomicAdd(&lcnt, 1);
            if (pos < SORTN) {
                // certainty >= 0 always, so |0x80000000 is a monotonic uint mapping
                unsigned int m = __float_as_uint(cert[b * NPIX + n]) | 0x80000000u;
                keys[pos] = ((unsigned long long)m << 32) |
                            (unsigned long long)(0xFFFFFFFFu - (unsigned)n);
            }
        }
    }
    __syncthreads();
    int L = lcnt < SORTN ? lcnt : SORTN;
    for (int i = tid; i < SORTN; i += 256)
        if (i >= L) keys[i] = 0ULL;   // sinks to the end (valid keys have top bit set)
    __syncthreads();
    // bitonic sort, descending
    for (int sz = 2; sz <= SORTN; sz <<= 1) {
        for (int j = sz >> 1; j > 0; j >>= 1) {
            for (int i = tid; i < SORTN; i += 256) {
                int ixj = i ^ j;
                if (ixj > i) {
                    unsigned long long a = keys[i], c = keys[ixj];
                    bool up = ((i & sz) == 0);
                    if ((a < c) == up) { keys[i] = c; keys[ixj] = a; }
                }
            }
            __syncthreads();
        }
    }
    int kv = kwant < L ? kwant : L;
    float accv[16];
#pragma unroll
    for (int d = 0; d < 16; ++d) accv[d] = 0.f;
    for (int i = tid; i < kv; i += 256) {
        unsigned pix = 0xFFFFFFFFu - (unsigned)(keys[i] & 0xFFFFFFFFull);
        for (int d = 0; d < D; ++d)
            accv[d] += feats[((size_t)(b * CHN + chan[d]) << 14) + pix];
    }
    for (int d = 0; d < 16; ++d) {
        red[tid] = accv[d]; __syncthreads();
        for (int s = 128; s > 0; s >>= 1) { if (tid < s) red[tid] += red[tid + s]; __syncthreads(); }
        if (tid == 0) pos_[p * 16 + d] = (d < D) ? (red[0] / (float)kv) : 0.f;
        __syncthreads();
    }
}

// class_intra_loss: sum((cos(pos_i,pos_j)+1)*[cls_i!=cls_j]) / #pairs ; also stores posnorm
__global__ __launch_bounds__(256) void k_intra(const int* __restrict__ plan,
                                               const float* __restrict__ pos_,
                                               float* __restrict__ posnorm,
                                               double* __restrict__ acc) {
    __shared__ float ppd[128 * 16];
    __shared__ float nr[128];
    __shared__ int cl[128];
    __shared__ double red[256];
    int tid = threadIdx.x;
    int P = plan[2], D = plan[3];
    const int* pcls = plan + 148;
    for (int i = tid; i < P * 16; i += 256) ppd[i] = pos_[i];
    __syncthreads();
    for (int p = tid; p < P; p += 256) {
        float s = 0;
        for (int d = 0; d < D; ++d) { float x = ppd[p * 16 + d]; s += x * x; }
        float nn = sqrtf(s);
        nr[p] = nn; posnorm[p] = nn; cl[p] = pcls[p];
    }
    __syncthreads();
    double num = 0; int cnt = 0;
    for (int idx = tid; idx < P * P; idx += 256) {
        int i = idx / P, j = idx - i * P;
        if (cl[i] != cl[j]) {
            float dot = 0;
            for (int d = 0; d < D; ++d) dot += ppd[i * 16 + d] * ppd[j * 16 + d];
            float cosm = dot / (nr[i] * nr[j]);
            num += (double)cosm + 1.0;
            cnt++;
        }
    }
    red[tid] = num; __syncthreads();
    for (int s = 128; s > 0; s >>= 1) { if (tid < s) red[tid] += red[tid + s]; __syncthreads(); }
    double totnum = red[0]; __syncthreads();
    red[tid] = (double)cnt; __syncthreads();
    for (int s = 128; s > 0; s >>= 1) { if (tid < s) red[tid] += red[tid + s]; __syncthreads(); }
    if (tid == 0) atomicAdd(acc, totnum / red[0]);
}

// class_inter_loss: mean over groups of per-group mean of (1 - cos(pixel_chans, pos_p))
// (full-population mean replaces the reference's random n_view subset; error ~3e-4)
__global__ __launch_bounds__(256) void k_inter(const float* __restrict__ feats,
                                               const int* __restrict__ predict,
                                               const int* __restrict__ plan,
                                               const float* __restrict__ pos_,
                                               const float* __restrict__ posnorm,
                                               double* __restrict__ acc) {
    __shared__ double red[256];
    int tid = threadIdx.x;
    int t = blockIdx.x * 256 + tid;
    int b = t >> 14, n = t & (NPIX - 1);
    int P = plan[2], D = plan[3];
    const int* chan = plan + 4;
    const int* pmap = plan + 276;
    const int* Lp = plan + 404;
    double term = 0;
    int v = predict[t];
    if (v >= 0 && v < NCLS) {
        int p = pmap[b * NCLS + v];
        if (p >= 0) {
            float dot = 0, nv = 0;
            for (int d = 0; d < D; ++d) {
                float x = feats[((size_t)(b * CHN + chan[d]) << 14) + n];
                float y = pos_[p * 16 + d];
                dot += x * y; nv += x * x;
            }
            float den = fmaxf(sqrtf(nv) * posnorm[p], 1e-8f);
            float cs = dot / den;
            term = (1.0 - (double)cs) / ((double)Lp[p] * (double)P);
        }
    }
    red[tid] = term; __syncthreads();
    for (int s = 128; s > 0; s >>= 1) { if (tid < s) red[tid] += red[tid + s]; __syncthreads(); }
    if (tid == 0) atomicAdd(acc, red[0]);
}

__global__ void k_finish(const double* __restrict__ acc, float* __restrict__ out) {
    out[0] = (float)acc[0];
}

extern "C" void kernel_launch(void* const* d_in, const int* in_sizes, int n_in,
                              void* d_out, int out_size, void* d_ws, size_t ws_size,
                              hipStream_t stream) {
    const float* feats  = (const float*)d_in[0];
    const int* predict  = (const int*)d_in[2];   // labels (d_in[1]) unused by the reference
    char* ws = (char*)d_ws;
    double* acc    = (double*)ws;
    int* counts    = (int*)(ws + 64);
    int* plan      = (int*)(ws + 1024);
    float* pos_    = (float*)(ws + 8192);
    float* posnorm = (float*)(ws + 16384);
    float* cert    = (float*)(ws + 32768);
    float* out     = (float*)d_out;

    hipMemsetAsync(ws, 0, 8192, stream);                      // acc + counts + plan
    k_hist  <<<512, 256, 0, stream>>>(predict, counts);
    k_plan  <<<1,   1,   0, stream>>>(counts, plan);
    k_cert  <<<128, 256, 0, stream>>>(feats, cert);
    k_topk  <<<128, 256, 0, stream>>>(feats, predict, cert, plan, pos_);
    k_intra <<<1,   256, 0, stream>>>(plan, pos_, posnorm, acc);
    k_inter <<<512, 256, 0, stream>>>(feats, predict, plan, pos_, posnorm, acc);
    k_finish<<<1,   1,   0, stream>>>(acc, out);
}

// Round 2
// 352.070 us; speedup vs baseline: 1.3777x; 1.3777x over previous
//
#include <hip/hip_runtime.h>
#include <math.h>

#define BB 8
#define NCLS 16
#define NPIX 16384
#define CHN 256
#define MAXV 200
#define SORTN 2048
#define NCHUNK 4   // channel chunks in k_cert1 (64 channels each)

typedef unsigned long long ull;

// ---------------- ws layout (bytes) ----------------
// 0       : double acc
// 64      : int counts[128]
// 1024    : int plan[536]: [0]=n_view [1]=k [2]=P [3]=D,
//           chan[16]@+4, pimg[128]@+20, pcls[128]@+148, pmap[128]@+276, Lp[128]@+404
// 4096    : ull  thrKey[128]
// 5632    : int  kvArr[128]
// 8192    : float pos_[2048]
// 16384   : float posnorm[128]
// 17408   : float pos_sum[2048]
// 32768   : float cert[131072]           (512 KB)
// 1048576 : float2 part[NCHUNK*8*16384]  (4 MB)   -> total ~5.25 MB

__global__ __launch_bounds__(256) void k_hist(const int* __restrict__ predict,
                                              int* __restrict__ counts) {
    __shared__ int h[NCLS];
    int tid = threadIdx.x;
    if (tid < NCLS) h[tid] = 0;
    __syncthreads();
    int base = blockIdx.x * 256;
    int b = base >> 14;
    int v = predict[base + tid];
    if (v >= 0 && v < NCLS) atomicAdd(&h[v], 1);
    __syncthreads();
    if (tid < NCLS && h[tid] > 0) atomicAdd(&counts[b * NCLS + tid], h[tid]);
}

__global__ void k_plan(const int* __restrict__ counts, int* __restrict__ plan) {
    int* chan = plan + 4;
    int* pimg = plan + 20;
    int* pcls = plan + 148;
    int* pmap = plan + 276;
    int* Lp   = plan + 404;
    int D = 0;
    for (int v = 0; v < NCLS; ++v) {
        int tot = 0;
        for (int b = 0; b < BB; ++b) tot += counts[b * NCLS + v];
        if (tot > 0) chan[D++] = v;
    }
    int nview = 0x7fffffff, P = 0;
    for (int b = 0; b < BB; ++b)
        for (int v = 0; v < NCLS; ++v) {
            int c = counts[b * NCLS + v];
            pmap[b * NCLS + v] = -1;
            if (c >= MAXV) {
                pmap[b * NCLS + v] = P;
                pimg[P] = b; pcls[P] = v; Lp[P] = c;
                if (c < nview) nview = c;
                ++P;
            }
        }
    plan[0] = nview; plan[1] = nview / 2; plan[2] = P; plan[3] = D;
}

// phase 1: per-(image, pixel-tile, channel-chunk) partial top-2
__global__ __launch_bounds__(256) void k_cert1(const float* __restrict__ feats,
                                               float2* __restrict__ part) {
    int bid = blockIdx.x;                  // 8 * 16 * NCHUNK = 512 blocks
    int chunk = bid & (NCHUNK - 1);
    int tile  = ((bid >> 2) & 15) * 1024;
    int b     = bid >> 6;
    int n4 = tile + threadIdx.x * 4;
    const float* fb = feats + (size_t)b * CHN * NPIX + n4;
    int c0 = chunk * (CHN / NCHUNK);
    float m1[4] = {-INFINITY, -INFINITY, -INFINITY, -INFINITY};
    float m2[4] = {-INFINITY, -INFINITY, -INFINITY, -INFINITY};
#pragma unroll 8
    for (int c = c0; c < c0 + CHN / NCHUNK; ++c) {
        const float4 x = *(const float4*)(fb + (size_t)c * NPIX);
        float xv[4] = {x.x, x.y, x.z, x.w};
#pragma unroll
        for (int q = 0; q < 4; ++q) {
            float val = xv[q];
            if (val > m1[q]) { m2[q] = m1[q]; m1[q] = val; }
            else if (val > m2[q]) m2[q] = val;
        }
    }
    float2* po = part + (((size_t)(b * NCHUNK + chunk)) << 14) + n4;
#pragma unroll
    for (int q = 0; q < 4; ++q) po[q] = make_float2(m1[q], m2[q]);
}

// phase 2: merge NCHUNK partials -> certainty
__global__ __launch_bounds__(256) void k_cert2(const float2* __restrict__ part,
                                               float* __restrict__ cert) {
    int t = blockIdx.x * 256 + threadIdx.x;   // 131072 threads
    int b = t >> 14, pix = t & (NPIX - 1);
    float m1 = -INFINITY, m2 = -INFINITY;
#pragma unroll
    for (int j = 0; j < NCHUNK; ++j) {
        float2 pm = part[(((size_t)(b * NCHUNK + j)) << 14) + pix];
        if (pm.x > m1) { m2 = fmaxf(m1, pm.y); m1 = pm.x; }
        else           { m2 = fmaxf(m2, pm.x); }
    }
    cert[t] = m1 - m2;
}

// one block per (b,v): gather unique 64-bit keys, MSD radix-select the kv-th
// largest -> threshold key (inclusion: key >= thr gives exactly kv pixels,
// matching top_k's earliest-index tie-break since keys embed ~pixel)
__global__ __launch_bounds__(256) void k_sel(const int* __restrict__ predict,
                                             const float* __restrict__ cert,
                                             const int* __restrict__ plan,
                                             ull* __restrict__ thrKey,
                                             int* __restrict__ kvArr) {
    __shared__ ull keys[SORTN];
    __shared__ int lcnt;
    __shared__ int hist[256];
    __shared__ ull sprefix;
    __shared__ int sremain;
    int tid = threadIdx.x;
    int b = blockIdx.x >> 4, v = blockIdx.x & 15;
    const int* pmap = plan + 276;
    int p = pmap[b * NCLS + v];
    if (p < 0) return;
    if (tid == 0) { lcnt = 0; sprefix = 0; }
    __syncthreads();
    for (int n = tid; n < NPIX; n += 256) {
        if (predict[b * NPIX + n] == v) {
            int pos = atomicAdd(&lcnt, 1);
            if (pos < SORTN) {
                unsigned int m = __float_as_uint(cert[b * NPIX + n]) | 0x80000000u;
                keys[pos] = ((ull)m << 32) | (ull)(0xFFFFFFFFu - (unsigned)n);
            }
        }
    }
    __syncthreads();
    int L = lcnt < SORTN ? lcnt : SORTN;
    int kv = plan[1] < L ? plan[1] : L;
    if (tid == 0) sremain = kv;
    __syncthreads();
    for (int shift = 56; shift >= 0; shift -= 8) {
        for (int i = tid; i < 256; i += 256) hist[i] = 0;
        __syncthreads();
        ull maskHi = (shift == 56) ? 0ULL : (~0ULL) << (shift + 8);
        ull pref = sprefix;
        int rem = sremain;
        for (int i = tid; i < L; i += 256) {
            ull kk = keys[i];
            if ((kk & maskHi) == pref) atomicAdd(&hist[(int)((kk >> shift) & 255)], 1);
        }
        __syncthreads();
        if (tid == 0) {
            int r = rem, bsel = 0;
            for (int bin = 255; bin >= 0; --bin) {
                if (hist[bin] >= r) { bsel = bin; break; }
                r -= hist[bin];
            }
            sprefix = pref | ((ull)bsel << shift);
            sremain = r;
        }
        __syncthreads();
    }
    if (tid == 0) { thrKey[p] = sprefix; kvArr[p] = kv; }
}

// one sweep over all pixels: pixels whose key >= group threshold contribute
// their 16 selected channels to pos_sum (LDS per-class accumulators first)
__global__ __launch_bounds__(256) void k_accum(const float* __restrict__ feats,
                                               const int* __restrict__ predict,
                                               const float* __restrict__ cert,
                                               const int* __restrict__ plan,
                                               const ull* __restrict__ thrKey,
                                               float* __restrict__ pos_sum) {
    __shared__ float gacc[NCLS * 16];
    int tid = threadIdx.x;
    int t = blockIdx.x * 256 + tid;
    int b = t >> 14, n = t & (NPIX - 1);
    const int* chan = plan + 4;
    const int* pmap = plan + 276;
    int D = plan[3];
    if (tid < NCLS * 16) gacc[tid] = 0.f;
    __syncthreads();
    int v = predict[t];
    if (v >= 0 && v < NCLS) {
        int p = pmap[b * NCLS + v];
        if (p >= 0) {
            unsigned int m = __float_as_uint(cert[t]) | 0x80000000u;
            ull key = ((ull)m << 32) | (ull)(0xFFFFFFFFu - (unsigned)n);
            if (key >= thrKey[p]) {
                for (int d = 0; d < D; ++d)
                    atomicAdd(&gacc[v * 16 + d],
                              feats[((size_t)(b * CHN + chan[d]) << 14) + n]);
            }
        }
    }
    __syncthreads();
    if (tid < NCLS * 16) {
        int vv = tid >> 4;
        int p = pmap[b * NCLS + vv];
        if (p >= 0 && gacc[tid] != 0.f) atomicAdd(&pos_sum[p * 16 + tid % 16], gacc[tid]);
    }
}

__global__ __launch_bounds__(256) void k_div(const int* __restrict__ plan,
                                             const float* __restrict__ pos_sum,
                                             const int* __restrict__ kvArr,
                                             float* __restrict__ pos_) {
    int i = threadIdx.x + blockIdx.x * 256;
    int P = plan[2];
    if (i < P * 16) pos_[i] = pos_sum[i] / (float)kvArr[i >> 4];
}

__global__ __launch_bounds__(256) void k_intra(const int* __restrict__ plan,
                                               const float* __restrict__ pos_,
                                               float* __restrict__ posnorm,
                                               double* __restrict__ acc) {
    __shared__ float ppd[128 * 16];
    __shared__ float nr[128];
    __shared__ int cl[128];
    __shared__ double red[256];
    int tid = threadIdx.x;
    int P = plan[2], D = plan[3];
    const int* pcls = plan + 148;
    for (int i = tid; i < P * 16; i += 256) ppd[i] = pos_[i];
    __syncthreads();
    for (int p = tid; p < P; p += 256) {
        float s = 0;
        for (int d = 0; d < D; ++d) { float x = ppd[p * 16 + d]; s += x * x; }
        float nn = sqrtf(s);
        nr[p] = nn; posnorm[p] = nn; cl[p] = pcls[p];
    }
    __syncthreads();
    double num = 0; int cnt = 0;
    for (int idx = tid; idx < P * P; idx += 256) {
        int i = idx / P, j = idx - i * P;
        if (cl[i] != cl[j]) {
            float dot = 0;
            for (int d = 0; d < D; ++d) dot += ppd[i * 16 + d] * ppd[j * 16 + d];
            num += (double)(dot / (nr[i] * nr[j])) + 1.0;
            cnt++;
        }
    }
    red[tid] = num; __syncthreads();
    for (int s = 128; s > 0; s >>= 1) { if (tid < s) red[tid] += red[tid + s]; __syncthreads(); }
    double totnum = red[0]; __syncthreads();
    red[tid] = (double)cnt; __syncthreads();
    for (int s = 128; s > 0; s >>= 1) { if (tid < s) red[tid] += red[tid + s]; __syncthreads(); }
    if (tid == 0) atomicAdd(acc, totnum / red[0]);
}

__global__ __launch_bounds__(256) void k_inter(const float* __restrict__ feats,
                                               const int* __restrict__ predict,
                                               const int* __restrict__ plan,
                                               const float* __restrict__ pos_,
                                               const float* __restrict__ posnorm,
                                               double* __restrict__ acc) {
    __shared__ double red[256];
    int tid = threadIdx.x;
    int t = blockIdx.x * 256 + tid;
    int b = t >> 14, n = t & (NPIX - 1);
    int P = plan[2], D = plan[3];
    const int* chan = plan + 4;
    const int* pmap = plan + 276;
    const int* Lp = plan + 404;
    double term = 0;
    int v = predict[t];
    if (v >= 0 && v < NCLS) {
        int p = pmap[b * NCLS + v];
        if (p >= 0) {
            float dot = 0, nv = 0;
            for (int d = 0; d < D; ++d) {
                float x = feats[((size_t)(b * CHN + chan[d]) << 14) + n];
                float y = pos_[p * 16 + d];
                dot += x * y; nv += x * x;
            }
            float den = fmaxf(sqrtf(nv) * posnorm[p], 1e-8f);
            term = (1.0 - (double)(dot / den)) / ((double)Lp[p] * (double)P);
        }
    }
    red[tid] = term; __syncthreads();
    for (int s = 128; s > 0; s >>= 1) { if (tid < s) red[tid] += red[tid + s]; __syncthreads(); }
    if (tid == 0) atomicAdd(acc, red[0]);
}

__global__ void k_finish(const double* __restrict__ acc, float* __restrict__ out) {
    out[0] = (float)acc[0];
}

// fallback single-phase cert (used only if ws_size is too small for partials)
__global__ __launch_bounds__(256) void k_cert_direct(const float* __restrict__ feats,
                                                     float* __restrict__ cert) {
    int t = blockIdx.x * 256 + threadIdx.x;
    int b = t >> 12;
    int n4 = (t & 4095) * 4;
    const float* fb = feats + (size_t)b * CHN * NPIX + n4;
    float m1[4] = {-INFINITY, -INFINITY, -INFINITY, -INFINITY};
    float m2[4] = {-INFINITY, -INFINITY, -INFINITY, -INFINITY};
    for (int c = 0; c < CHN; ++c) {
        const float4 x = *(const float4*)(fb + (size_t)c * NPIX);
        float xv[4] = {x.x, x.y, x.z, x.w};
#pragma unroll
        for (int q = 0; q < 4; ++q) {
            float val = xv[q];
            if (val > m1[q]) { m2[q] = m1[q]; m1[q] = val; }
            else if (val > m2[q]) m2[q] = val;
        }
    }
    float4 o = {m1[0] - m2[0], m1[1] - m2[1], m1[2] - m2[2], m1[3] - m2[3]};
    *(float4*)(cert + b * NPIX + n4) = o;
}

extern "C" void kernel_launch(void* const* d_in, const int* in_sizes, int n_in,
                              void* d_out, int out_size, void* d_ws, size_t ws_size,
                              hipStream_t stream) {
    const float* feats  = (const float*)d_in[0];
    const int* predict  = (const int*)d_in[2];
    char* ws = (char*)d_ws;
    double* acc     = (double*)ws;
    int* counts     = (int*)(ws + 64);
    int* plan       = (int*)(ws + 1024);
    ull* thrKey     = (ull*)(ws + 4096);
    int* kvArr      = (int*)(ws + 5632);
    float* pos_     = (float*)(ws + 8192);
    float* posnorm  = (float*)(ws + 16384);
    float* pos_sum  = (float*)(ws + 17408);
    float* cert     = (float*)(ws + 32768);
    float2* part    = (float2*)(ws + 1048576);
    float* out      = (float*)d_out;

    hipMemsetAsync(ws, 0, 32768, stream);
    k_hist  <<<512, 256, 0, stream>>>(predict, counts);
    k_plan  <<<1,   1,   0, stream>>>(counts, plan);
    if (ws_size >= 1048576 + (size_t)NCHUNK * BB * NPIX * sizeof(float2)) {
        k_cert1 <<<BB * 16 * NCHUNK, 256, 0, stream>>>(feats, part);
        k_cert2 <<<512, 256, 0, stream>>>(part, cert);
    } else {
        k_cert_direct <<<128, 256, 0, stream>>>(feats, cert);
    }
    k_sel   <<<128, 256, 0, stream>>>(predict, cert, plan, thrKey, kvArr);
    k_accum <<<512, 256, 0, stream>>>(feats, predict, cert, plan, thrKey, pos_sum);
    k_div   <<<8,   256, 0, stream>>>(plan, pos_sum, kvArr, pos_);
    k_intra <<<1,   256, 0, stream>>>(plan, pos_, posnorm, acc);
    k_inter <<<512, 256, 0, stream>>>(feats, predict, plan, pos_, posnorm, acc);
    k_finish<<<1,   1,   0, stream>>>(acc, out);
}

// Round 3
// 323.413 us; speedup vs baseline: 1.4998x; 1.0886x over previous
//
#include <hip/hip_runtime.h>
#include <math.h>

#define BB 8
#define NCLS 16
#define NPIX 16384
#define CHN 256
#define MAXV 200
#define SORTN 2048

typedef unsigned long long ull;

// ---------------- ws layout (bytes) ----------------
// 0       : double acc
// 64      : int counts[128]
// 1024    : int plan[536]: [0]=n_view [1]=k [2]=P [3]=D,
//           chan[16]@+4, pimg[128]@+20, pcls[128]@+148, pmap[128]@+276, Lp[128]@+404
// 8192    : float pos_[2048]
// 16384   : float posnorm[128]
// 32768   : float cert[131072]           (512 KB)
// 1048576 : float2 part[NC*8*16384]      (4 or 8 MB)

__global__ __launch_bounds__(256) void k_hist(const int* __restrict__ predict,
                                              int* __restrict__ counts) {
    __shared__ int h[NCLS];
    int tid = threadIdx.x;
    if (tid < NCLS) h[tid] = 0;
    __syncthreads();
    int base = blockIdx.x * 256;
    int b = base >> 14;
    int v = predict[base + tid];
    if (v >= 0 && v < NCLS) atomicAdd(&h[v], 1);
    __syncthreads();
    if (tid < NCLS && h[tid] > 0) atomicAdd(&counts[b * NCLS + tid], h[tid]);
}

// parallel plan: LDS-staged counts, prefix-scan group indexing, min-reduce n_view
__global__ __launch_bounds__(256) void k_plan(const int* __restrict__ counts,
                                              int* __restrict__ plan) {
    __shared__ int c[128];
    __shared__ int sc[128];
    __shared__ int mn[128];
    __shared__ int present[NCLS];
    int tid = threadIdx.x;
    int* chan = plan + 4;
    int* pimg = plan + 20;
    int* pcls = plan + 148;
    int* pmap = plan + 276;
    int* Lp   = plan + 404;
    if (tid < 128) c[tid] = counts[tid];
    if (tid < NCLS) present[tid] = 0;
    __syncthreads();
    int e = 0;
    if (tid < 128) {
        if (c[tid] > 0) atomicOr(&present[tid & 15], 1);
        e = (c[tid] >= MAXV) ? 1 : 0;
        sc[tid] = e;
        mn[tid] = e ? c[tid] : 0x7fffffff;
    }
    __syncthreads();
    for (int off = 1; off < 128; off <<= 1) {          // inclusive prefix over (b,v) order
        int add = 0;
        if (tid < 128 && tid >= off) add = sc[tid - off];
        __syncthreads();
        if (tid < 128) sc[tid] += add;
        __syncthreads();
    }
    for (int s = 64; s > 0; s >>= 1) {
        if (tid < s) mn[tid] = min(mn[tid], mn[tid + s]);
        __syncthreads();
    }
    if (tid < 128) {
        pmap[tid] = e ? (sc[tid] - 1) : -1;
        if (e) {
            int p = sc[tid] - 1;
            pimg[p] = tid >> 4; pcls[p] = tid & 15; Lp[p] = c[tid];
        }
    }
    if (tid == 0) {
        int D = 0;
        for (int v = 0; v < NCLS; ++v) if (present[v]) chan[D++] = v;
        int nview = mn[0];
        plan[0] = nview; plan[1] = nview / 2; plan[2] = sc[127]; plan[3] = D;
    }
}

// phase 1: per-(image, pixel-tile, channel-chunk) partial top-2
template <int NC>
__global__ __launch_bounds__(256) void k_cert1(const float* __restrict__ feats,
                                               float2* __restrict__ part) {
    int bid = blockIdx.x;                  // BB * 16 * NC blocks
    int chunk = bid % NC;
    int tile  = (bid / NC) % 16;
    int b     = bid / (NC * 16);
    int n4 = tile * 1024 + threadIdx.x * 4;
    const float* fb = feats + (size_t)b * CHN * NPIX + n4;
    int c0 = chunk * (CHN / NC);
    float m1[4] = {-INFINITY, -INFINITY, -INFINITY, -INFINITY};
    float m2[4] = {-INFINITY, -INFINITY, -INFINITY, -INFINITY};
#pragma unroll 8
    for (int c = c0; c < c0 + CHN / NC; ++c) {
        const float4 x = *(const float4*)(fb + (size_t)c * NPIX);
        float xv[4] = {x.x, x.y, x.z, x.w};
#pragma unroll
        for (int q = 0; q < 4; ++q) {
            float val = xv[q];
            if (val > m1[q]) { m2[q] = m1[q]; m1[q] = val; }
            else if (val > m2[q]) m2[q] = val;
        }
    }
    float2* po = part + (((size_t)(b * NC + chunk)) << 14) + n4;
#pragma unroll
    for (int q = 0; q < 4; ++q) po[q] = make_float2(m1[q], m2[q]);
}

template <int NC>
__global__ __launch_bounds__(256) void k_cert2(const float2* __restrict__ part,
                                               float* __restrict__ cert) {
    int t = blockIdx.x * 256 + threadIdx.x;
    int b = t >> 14, pix = t & (NPIX - 1);
    float m1 = -INFINITY, m2 = -INFINITY;
#pragma unroll
    for (int j = 0; j < NC; ++j) {
        float2 pm = part[(((size_t)(b * NC + j)) << 14) + pix];
        if (pm.x > m1) { m2 = fmaxf(m1, pm.y); m1 = pm.x; }
        else           { m2 = fmaxf(m2, pm.x); }
    }
    cert[t] = m1 - m2;
}

// one block per (b,v): wave-aggregated key gather, parallel MSD radix-select,
// then in-block top-k channel accumulation -> pos_ (selection: key >= thr,
// exactly matching top_k's earliest-index tie-break via embedded ~pixel)
__global__ __launch_bounds__(256) void k_sel(const float* __restrict__ feats,
                                             const int* __restrict__ predict,
                                             const float* __restrict__ cert,
                                             const int* __restrict__ plan,
                                             float* __restrict__ pos_) {
    __shared__ ull keys[SORTN];
    __shared__ int lcnt;
    __shared__ int hist[256];
    __shared__ int scan[256];
    __shared__ ull sprefix;
    __shared__ int sremain;
    __shared__ float wacc[4][16];
    int tid = threadIdx.x;
    int lane = tid & 63, wv = tid >> 6;
    int b = blockIdx.x >> 4, v = blockIdx.x & 15;
    const int* chan = plan + 4;
    const int* pmap = plan + 276;
    int p = pmap[b * NCLS + v];
    if (p < 0) return;
    if (tid == 0) { lcnt = 0; sprefix = 0; }
    __syncthreads();
    for (int n = tid; n < NPIX; n += 256) {
        bool match = (predict[b * NPIX + n] == v);
        ull mask = __ballot(match);
        if (mask) {
            int leader = __ffsll((long long)mask) - 1;
            int basepos;
            if (lane == leader) basepos = atomicAdd(&lcnt, __popcll(mask));
            basepos = __shfl(basepos, leader, 64);
            if (match) {
                int pos = basepos + __popcll(mask & ((1ull << lane) - 1));
                if (pos < SORTN) {
                    unsigned int m = __float_as_uint(cert[b * NPIX + n]) | 0x80000000u;
                    keys[pos] = ((ull)m << 32) | (ull)(0xFFFFFFFFu - (unsigned)n);
                }
            }
        }
    }
    __syncthreads();
    int L = lcnt < SORTN ? lcnt : SORTN;
    int kv = plan[1] < L ? plan[1] : L;
    int D = plan[3];
    if (tid == 0) sremain = kv;
    __syncthreads();
    for (int shift = 56; shift >= 0; shift -= 8) {
        hist[tid] = 0;
        __syncthreads();
        ull pref = sprefix;                 // stable: written before prev pass's barrier
        int rem = sremain;
        ull maskHi = (shift == 56) ? 0ULL : (~0ULL) << (shift + 8);
        for (int i = tid; i < L; i += 256) {
            ull kk = keys[i];
            if ((kk & maskHi) == pref) atomicAdd(&hist[(int)((kk >> shift) & 255)], 1);
        }
        __syncthreads();
        scan[tid] = hist[tid];
        __syncthreads();
        for (int off = 1; off < 256; off <<= 1) {   // inclusive suffix sum
            int add = (tid + off < 256) ? scan[tid + off] : 0;
            __syncthreads();
            scan[tid] += add;
            __syncthreads();
        }
        // crossing bin: scan[bin] >= rem > scan[bin+1]
        if (scan[tid] >= rem && (tid == 255 || scan[tid + 1] < rem)) {
            sprefix = pref | ((ull)tid << shift);
            sremain = rem - ((tid == 255) ? 0 : scan[tid + 1]);
        }
        __syncthreads();
    }
    ull thr = sprefix;
    // accumulate selected pixels' channels
    float accv[16];
#pragma unroll
    for (int d = 0; d < 16; ++d) accv[d] = 0.f;
    const float* fbase = feats + ((size_t)b * CHN << 14);
    for (int i = tid; i < L; i += 256) {
        ull kk = keys[i];
        if (kk >= thr) {
            unsigned pix = 0xFFFFFFFFu - (unsigned)(kk & 0xFFFFFFFFull);
            for (int d = 0; d < D; ++d)
                accv[d] += fbase[((size_t)chan[d] << 14) + pix];
        }
    }
#pragma unroll
    for (int d = 0; d < 16; ++d)
        for (int off = 32; off > 0; off >>= 1)
            accv[d] += __shfl_down(accv[d], off, 64);
    if (lane == 0)
#pragma unroll
        for (int d = 0; d < 16; ++d) wacc[wv][d] = accv[d];
    __syncthreads();
    if (tid < 16) {
        float s = wacc[0][tid] + wacc[1][tid] + wacc[2][tid] + wacc[3][tid];
        pos_[p * 16 + tid] = (tid < D) ? s / (float)kv : 0.f;
    }
}

__global__ __launch_bounds__(256) void k_intra(const int* __restrict__ plan,
                                               const float* __restrict__ pos_,
                                               float* __restrict__ posnorm,
                                               double* __restrict__ acc) {
    __shared__ float ppd[128 * 16];
    __shared__ float nr[128];
    __shared__ int cl[128];
    __shared__ double red[256];
    int tid = threadIdx.x;
    int P = plan[2], D = plan[3];
    const int* pcls = plan + 148;
    for (int i = tid; i < P * 16; i += 256) ppd[i] = pos_[i];
    __syncthreads();
    for (int p = tid; p < P; p += 256) {
        float s = 0;
        for (int d = 0; d < D; ++d) { float x = ppd[p * 16 + d]; s += x * x; }
        float nn = sqrtf(s);
        nr[p] = nn; posnorm[p] = nn; cl[p] = pcls[p];
    }
    __syncthreads();
    double num = 0; int cnt = 0;
    for (int idx = tid; idx < P * P; idx += 256) {
        int i = idx / P, j = idx - i * P;
        if (cl[i] != cl[j]) {
            float dot = 0;
            for (int d = 0; d < D; ++d) dot += ppd[i * 16 + d] * ppd[j * 16 + d];
            num += (double)(dot / (nr[i] * nr[j])) + 1.0;
            cnt++;
        }
    }
    red[tid] = num; __syncthreads();
    for (int s = 128; s > 0; s >>= 1) { if (tid < s) red[tid] += red[tid + s]; __syncthreads(); }
    double totnum = red[0]; __syncthreads();
    red[tid] = (double)cnt; __syncthreads();
    for (int s = 128; s > 0; s >>= 1) { if (tid < s) red[tid] += red[tid + s]; __syncthreads(); }
    if (tid == 0) atomicAdd(acc, totnum / red[0]);
}

__global__ __launch_bounds__(256) void k_inter(const float* __restrict__ feats,
                                               const int* __restrict__ predict,
                                               const int* __restrict__ plan,
                                               const float* __restrict__ pos_,
                                               const float* __restrict__ posnorm,
                                               double* __restrict__ acc) {
    __shared__ double red[256];
    int tid = threadIdx.x;
    int t = blockIdx.x * 256 + tid;
    int b = t >> 14, n = t & (NPIX - 1);
    int P = plan[2], D = plan[3];
    const int* chan = plan + 4;
    const int* pmap = plan + 276;
    const int* Lp = plan + 404;
    double term = 0;
    int v = predict[t];
    if (v >= 0 && v < NCLS) {
        int p = pmap[b * NCLS + v];
        if (p >= 0) {
            float dot = 0, nv = 0;
            for (int d = 0; d < D; ++d) {
                float x = feats[((size_t)(b * CHN + chan[d]) << 14) + n];
                float y = pos_[p * 16 + d];
                dot += x * y; nv += x * x;
            }
            float den = fmaxf(sqrtf(nv) * posnorm[p], 1e-8f);
            term = (1.0 - (double)(dot / den)) / ((double)Lp[p] * (double)P);
        }
    }
    red[tid] = term; __syncthreads();
    for (int s = 128; s > 0; s >>= 1) { if (tid < s) red[tid] += red[tid + s]; __syncthreads(); }
    if (tid == 0) atomicAdd(acc, red[0]);
}

__global__ void k_finish(const double* __restrict__ acc, float* __restrict__ out) {
    out[0] = (float)acc[0];
}

// fallback single-phase cert (only if ws is too small for partials)
__global__ __launch_bounds__(256) void k_cert_direct(const float* __restrict__ feats,
                                                     float* __restrict__ cert) {
    int t = blockIdx.x * 256 + threadIdx.x;
    int b = t >> 12;
    int n4 = (t & 4095) * 4;
    const float* fb = feats + (size_t)b * CHN * NPIX + n4;
    float m1[4] = {-INFINITY, -INFINITY, -INFINITY, -INFINITY};
    float m2[4] = {-INFINITY, -INFINITY, -INFINITY, -INFINITY};
    for (int c = 0; c < CHN; ++c) {
        const float4 x = *(const float4*)(fb + (size_t)c * NPIX);
        float xv[4] = {x.x, x.y, x.z, x.w};
#pragma unroll
        for (int q = 0; q < 4; ++q) {
            float val = xv[q];
            if (val > m1[q]) { m2[q] = m1[q]; m1[q] = val; }
            else if (val > m2[q]) m2[q] = val;
        }
    }
    float4 o = {m1[0] - m2[0], m1[1] - m2[1], m1[2] - m2[2], m1[3] - m2[3]};
    *(float4*)(cert + b * NPIX + n4) = o;
}

extern "C" void kernel_launch(void* const* d_in, const int* in_sizes, int n_in,
                              void* d_out, int out_size, void* d_ws, size_t ws_size,
                              hipStream_t stream) {
    const float* feats  = (const float*)d_in[0];
    const int* predict  = (const int*)d_in[2];
    char* ws = (char*)d_ws;
    double* acc     = (double*)ws;
    int* counts     = (int*)(ws + 64);
    int* plan       = (int*)(ws + 1024);
    float* pos_     = (float*)(ws + 8192);
    float* posnorm  = (float*)(ws + 16384);
    float* cert     = (float*)(ws + 32768);
    float2* part    = (float2*)(ws + 1048576);
    float* out      = (float*)d_out;

    hipMemsetAsync(ws, 0, 8192, stream);
    k_hist  <<<512, 256, 0, stream>>>(predict, counts);
    k_plan  <<<1,   256, 0, stream>>>(counts, plan);
    size_t need8 = 1048576 + (size_t)8 * BB * NPIX * sizeof(float2);
    size_t need4 = 1048576 + (size_t)4 * BB * NPIX * sizeof(float2);
    if (ws_size >= need8) {
        k_cert1<8> <<<BB * 16 * 8, 256, 0, stream>>>(feats, part);
        k_cert2<8> <<<512, 256, 0, stream>>>(part, cert);
    } else if (ws_size >= need4) {
        k_cert1<4> <<<BB * 16 * 4, 256, 0, stream>>>(feats, part);
        k_cert2<4> <<<512, 256, 0, stream>>>(part, cert);
    } else {
        k_cert_direct <<<128, 256, 0, stream>>>(feats, cert);
    }
    k_sel   <<<128, 256, 0, stream>>>(feats, predict, cert, plan, pos_);
    k_intra <<<1,   256, 0, stream>>>(plan, pos_, posnorm, acc);
    k_inter <<<512, 256, 0, stream>>>(feats, predict, plan, pos_, posnorm, acc);
    k_finish<<<1,   1,   0, stream>>>(acc, out);
}

// Round 4
// 280.090 us; speedup vs baseline: 1.7318x; 1.1547x over previous
//
#include <hip/hip_runtime.h>
#include <math.h>

#define BB 8
#define NCLS 16
#define NPIX 16384
#define CHN 256
#define MAXV 200
#define SORTN 2048

typedef unsigned long long ull;

// ---------------- ws layout (bytes) ----------------
// 0       : double acc
// 64      : int counts[128]
// 1024    : int plan[536]: [0]=n_view [1]=k [2]=P [3]=D,
//           chan[16]@+4, pimg[128]@+20, pcls[128]@+148, pmap[128]@+276, Lp[128]@+404
// 4096    : ull thrKey[128]
// 8192    : float pos_sum[2048]   (zeroed)
// 16384   : float posnorm[128]
// 32768   : float cert[131072]    (512 KB)
// 1048576 : float2 part[NC*8*16384]

__global__ __launch_bounds__(256) void k_hist(const int* __restrict__ predict,
                                              int* __restrict__ counts) {
    __shared__ int h[NCLS];
    int tid = threadIdx.x;
    if (tid < NCLS) h[tid] = 0;
    __syncthreads();
    int base = blockIdx.x * 256;
    int b = base >> 14;
    int v = predict[base + tid];
    if (v >= 0 && v < NCLS) atomicAdd(&h[v], 1);
    __syncthreads();
    if (tid < NCLS && h[tid] > 0) atomicAdd(&counts[b * NCLS + tid], h[tid]);
}

__global__ __launch_bounds__(256) void k_plan(const int* __restrict__ counts,
                                              int* __restrict__ plan) {
    __shared__ int c[128];
    __shared__ int sc[128];
    __shared__ int mn[128];
    __shared__ int present[NCLS];
    int tid = threadIdx.x;
    int* chan = plan + 4;
    int* pimg = plan + 20;
    int* pcls = plan + 148;
    int* pmap = plan + 276;
    int* Lp   = plan + 404;
    if (tid < 128) c[tid] = counts[tid];
    if (tid < NCLS) present[tid] = 0;
    __syncthreads();
    int e = 0;
    if (tid < 128) {
        if (c[tid] > 0) atomicOr(&present[tid & 15], 1);
        e = (c[tid] >= MAXV) ? 1 : 0;
        sc[tid] = e;
        mn[tid] = e ? c[tid] : 0x7fffffff;
    }
    __syncthreads();
    for (int off = 1; off < 128; off <<= 1) {
        int add = 0;
        if (tid < 128 && tid >= off) add = sc[tid - off];
        __syncthreads();
        if (tid < 128) sc[tid] += add;
        __syncthreads();
    }
    for (int s = 64; s > 0; s >>= 1) {
        if (tid < s) mn[tid] = min(mn[tid], mn[tid + s]);
        __syncthreads();
    }
    if (tid < 128) {
        pmap[tid] = e ? (sc[tid] - 1) : -1;
        if (e) {
            int p = sc[tid] - 1;
            pimg[p] = tid >> 4; pcls[p] = tid & 15; Lp[p] = c[tid];
        }
    }
    if (tid == 0) {
        int D = 0;
        for (int v = 0; v < NCLS; ++v) if (present[v]) chan[D++] = v;
        int nview = mn[0];
        plan[0] = nview; plan[1] = nview / 2; plan[2] = sc[127]; plan[3] = D;
    }
}

template <int NC>
__global__ __launch_bounds__(256) void k_cert1(const float* __restrict__ feats,
                                               float2* __restrict__ part) {
    int bid = blockIdx.x;                  // BB * 16 * NC blocks
    int chunk = bid % NC;
    int tile  = (bid / NC) % 16;
    int b     = bid / (NC * 16);
    int n4 = tile * 1024 + threadIdx.x * 4;
    const float* fb = feats + (size_t)b * CHN * NPIX + n4;
    int c0 = chunk * (CHN / NC);
    float m1[4] = {-INFINITY, -INFINITY, -INFINITY, -INFINITY};
    float m2[4] = {-INFINITY, -INFINITY, -INFINITY, -INFINITY};
#pragma unroll 8
    for (int c = c0; c < c0 + CHN / NC; ++c) {
        const float4 x = *(const float4*)(fb + (size_t)c * NPIX);
        float xv[4] = {x.x, x.y, x.z, x.w};
#pragma unroll
        for (int q = 0; q < 4; ++q) {
            float val = xv[q];
            if (val > m1[q]) { m2[q] = m1[q]; m1[q] = val; }
            else if (val > m2[q]) m2[q] = val;
        }
    }
    float2* po = part + (((size_t)(b * NC + chunk)) << 14) + n4;
#pragma unroll
    for (int q = 0; q < 4; ++q) po[q] = make_float2(m1[q], m2[q]);
}

template <int NC>
__global__ __launch_bounds__(256) void k_cert2(const float2* __restrict__ part,
                                               float* __restrict__ cert) {
    int t = blockIdx.x * 256 + threadIdx.x;
    int b = t >> 14, pix = t & (NPIX - 1);
    float m1 = -INFINITY, m2 = -INFINITY;
#pragma unroll
    for (int j = 0; j < NC; ++j) {
        float2 pm = part[(((size_t)(b * NC + j)) << 14) + pix];
        if (pm.x > m1) { m2 = fmaxf(m1, pm.y); m1 = pm.x; }
        else           { m2 = fmaxf(m2, pm.x); }
    }
    cert[t] = m1 - m2;
}

// selection only: per-(b,v) radix-select the kv-th largest 64-bit key ->
// threshold (key >= thr selects exactly kv pixels, tie-break = lowest pixel
// index, matching top_k). Early-exits when low bits are irrelevant.
__global__ __launch_bounds__(512) void k_sel(const int* __restrict__ predict,
                                             const float* __restrict__ cert,
                                             const int* __restrict__ plan,
                                             ull* __restrict__ thrKey) {
    __shared__ ull keys[SORTN];
    __shared__ int whist[8][256];
    __shared__ int scan[257];
    __shared__ int wtot[4];
    __shared__ int lcnt;
    __shared__ ull sprefix;
    __shared__ int sremain;
    __shared__ int sdone;
    int tid = threadIdx.x;
    int lane = tid & 63, wv = tid >> 6;
    int b = blockIdx.x >> 4, v = blockIdx.x & 15;
    const int* pmap = plan + 276;
    int p = pmap[b * NCLS + v];
    if (p < 0) return;
    if (tid == 0) { lcnt = 0; sprefix = 0; sdone = 0; }
    __syncthreads();
    for (int n = tid; n < NPIX; n += 512) {
        bool match = (predict[b * NPIX + n] == v);
        ull mask = __ballot(match);
        if (mask) {
            int leader = __ffsll((long long)mask) - 1;
            int basepos = 0;
            if (lane == leader) basepos = atomicAdd(&lcnt, __popcll(mask));
            basepos = __shfl(basepos, leader, 64);
            if (match) {
                int pos = basepos + __popcll(mask & ((1ull << lane) - 1));
                if (pos < SORTN) {
                    unsigned int m = __float_as_uint(cert[b * NPIX + n]) | 0x80000000u;
                    keys[pos] = ((ull)m << 32) | (ull)(0xFFFFFFFFu - (unsigned)n);
                }
            }
        }
    }
    __syncthreads();
    int L = lcnt < SORTN ? lcnt : SORTN;
    int kv = plan[1] < L ? plan[1] : L;
    if (tid == 0) sremain = kv;
    __syncthreads();
    for (int shift = 56; shift >= 0; shift -= 8) {
        if (sdone) break;                       // uniform: read after barrier
        for (int i = tid; i < 8 * 256; i += 512) ((int*)whist)[i] = 0;
        ull pref = sprefix;                     // stable: written before last barrier
        int rem = sremain;
        __syncthreads();
        ull maskHi = (shift == 56) ? 0ULL : (~0ULL) << (shift + 8);
        for (int i = tid; i < L; i += 512) {
            ull kk = keys[i];
            if ((kk & maskHi) == pref)
                atomicAdd(&whist[wv][(int)((kk >> shift) & 255)], 1);
        }
        __syncthreads();
        int s = 0;
        if (tid < 256) {                        // waves 0..3 wholly active
            for (int w = 0; w < 8; ++w) s += whist[w][tid];
            for (int off = 1; off < 64; off <<= 1) {   // within-wave suffix scan
                int o = __shfl_down(s, off, 64);
                if (lane + off < 64) s += o;
            }
            if (lane == 0) wtot[wv] = s;
        }
        __syncthreads();
        if (tid < 256) {
            int offs = 0;
            for (int w2 = wv + 1; w2 < 4; ++w2) offs += wtot[w2];
            s += offs;
            scan[tid] = s;
            if (tid == 0) scan[256] = 0;
        }
        __syncthreads();
        if (tid < 256) {
            int nxt = scan[tid + 1];
            if (s >= rem && nxt < rem) {        // crossing bin
                sprefix = pref | ((ull)tid << shift);
                sremain = rem - nxt;
                if (s == rem) sdone = 1;        // whole bin taken: low bits free
            }
        }
        __syncthreads();
    }
    if (tid == 0) thrKey[p] = sprefix;
}

// coalesced sweep: every pixel tests key >= thr of its group; selected pixels
// add their D channels into LDS per-class accumulators, then one global
// atomic per (class,chan) per block. pos_sum is the UNNORMALIZED mean
// (both downstream cosines are scale-invariant).
__global__ __launch_bounds__(512) void k_accum(const float* __restrict__ feats,
                                               const int* __restrict__ predict,
                                               const float* __restrict__ cert,
                                               const int* __restrict__ plan,
                                               const ull* __restrict__ thrKey,
                                               float* __restrict__ pos_sum) {
    __shared__ float gacc[NCLS * 16];
    int tid = threadIdx.x;
    int t = blockIdx.x * 512 + tid;     // 256 blocks, block within one image
    int b = (blockIdx.x * 512) >> 14;
    int n = t & (NPIX - 1);
    const int* chan = plan + 4;
    const int* pmap = plan + 276;
    int D = plan[3];
    if (tid < NCLS * 16) gacc[tid] = 0.f;
    __syncthreads();
    int v = predict[t];
    if (v >= 0 && v < NCLS) {
        int p = pmap[b * NCLS + v];
        if (p >= 0) {
            unsigned int m = __float_as_uint(cert[t]) | 0x80000000u;
            ull key = ((ull)m << 32) | (ull)(0xFFFFFFFFu - (unsigned)n);
            if (key >= thrKey[p]) {
                for (int d = 0; d < D; ++d)
                    atomicAdd(&gacc[v * 16 + d],
                              feats[((size_t)(b * CHN + chan[d]) << 14) + n]);
            }
        }
    }
    __syncthreads();
    if (tid < NCLS * 16) {
        int p = pmap[b * NCLS + (tid >> 4)];
        if (p >= 0 && gacc[tid] != 0.f) atomicAdd(&pos_sum[p * 16 + (tid & 15)], gacc[tid]);
    }
}

__global__ __launch_bounds__(256) void k_intra(const int* __restrict__ plan,
                                               const float* __restrict__ pos_,
                                               float* __restrict__ posnorm,
                                               double* __restrict__ acc) {
    __shared__ float ppd[128 * 16];
    __shared__ float nr[128];
    __shared__ int cl[128];
    __shared__ double red[256];
    int tid = threadIdx.x;
    int P = plan[2], D = plan[3];
    const int* pcls = plan + 148;
    for (int i = tid; i < P * 16; i += 256) ppd[i] = pos_[i];
    __syncthreads();
    for (int p = tid; p < P; p += 256) {
        float s = 0;
        for (int d = 0; d < D; ++d) { float x = ppd[p * 16 + d]; s += x * x; }
        float nn = sqrtf(s);
        nr[p] = nn; posnorm[p] = nn; cl[p] = pcls[p];
    }
    __syncthreads();
    double num = 0; int cnt = 0;
    for (int idx = tid; idx < P * P; idx += 256) {
        int i = idx / P, j = idx - i * P;
        if (cl[i] != cl[j]) {
            float dot = 0;
            for (int d = 0; d < D; ++d) dot += ppd[i * 16 + d] * ppd[j * 16 + d];
            num += (double)(dot / (nr[i] * nr[j])) + 1.0;
            cnt++;
        }
    }
    red[tid] = num; __syncthreads();
    for (int s = 128; s > 0; s >>= 1) { if (tid < s) red[tid] += red[tid + s]; __syncthreads(); }
    double totnum = red[0]; __syncthreads();
    red[tid] = (double)cnt; __syncthreads();
    for (int s = 128; s > 0; s >>= 1) { if (tid < s) red[tid] += red[tid + s]; __syncthreads(); }
    if (tid == 0) atomicAdd(acc, totnum / red[0]);
}

__global__ __launch_bounds__(256) void k_inter(const float* __restrict__ feats,
                                               const int* __restrict__ predict,
                                               const int* __restrict__ plan,
                                               const float* __restrict__ pos_,
                                               const float* __restrict__ posnorm,
                                               double* __restrict__ acc) {
    __shared__ double red[256];
    int tid = threadIdx.x;
    int t = blockIdx.x * 256 + tid;
    int b = t >> 14, n = t & (NPIX - 1);
    int P = plan[2], D = plan[3];
    const int* chan = plan + 4;
    const int* pmap = plan + 276;
    const int* Lp = plan + 404;
    double term = 0;
    int v = predict[t];
    if (v >= 0 && v < NCLS) {
        int p = pmap[b * NCLS + v];
        if (p >= 0) {
            float dot = 0, nv = 0;
            for (int d = 0; d < D; ++d) {
                float x = feats[((size_t)(b * CHN + chan[d]) << 14) + n];
                float y = pos_[p * 16 + d];
                dot += x * y; nv += x * x;
            }
            float den = fmaxf(sqrtf(nv) * posnorm[p], 1e-8f);
            term = (1.0 - (double)(dot / den)) / ((double)Lp[p] * (double)P);
        }
    }
    red[tid] = term; __syncthreads();
    for (int s = 128; s > 0; s >>= 1) { if (tid < s) red[tid] += red[tid + s]; __syncthreads(); }
    if (tid == 0) atomicAdd(acc, red[0]);
}

__global__ void k_finish(const double* __restrict__ acc, float* __restrict__ out) {
    out[0] = (float)acc[0];
}

// fallback single-phase cert (only if ws is too small for partials)
__global__ __launch_bounds__(256) void k_cert_direct(const float* __restrict__ feats,
                                                     float* __restrict__ cert) {
    int t = blockIdx.x * 256 + threadIdx.x;
    int b = t >> 12;
    int n4 = (t & 4095) * 4;
    const float* fb = feats + (size_t)b * CHN * NPIX + n4;
    float m1[4] = {-INFINITY, -INFINITY, -INFINITY, -INFINITY};
    float m2[4] = {-INFINITY, -INFINITY, -INFINITY, -INFINITY};
    for (int c = 0; c < CHN; ++c) {
        const float4 x = *(const float4*)(fb + (size_t)c * NPIX);
        float xv[4] = {x.x, x.y, x.z, x.w};
#pragma unroll
        for (int q = 0; q < 4; ++q) {
            float val = xv[q];
            if (val > m1[q]) { m2[q] = m1[q]; m1[q] = val; }
            else if (val > m2[q]) m2[q] = val;
        }
    }
    float4 o = {m1[0] - m2[0], m1[1] - m2[1], m1[2] - m2[2], m1[3] - m2[3]};
    *(float4*)(cert + b * NPIX + n4) = o;
}

extern "C" void kernel_launch(void* const* d_in, const int* in_sizes, int n_in,
                              void* d_out, int out_size, void* d_ws, size_t ws_size,
                              hipStream_t stream) {
    const float* feats  = (const float*)d_in[0];
    const int* predict  = (const int*)d_in[2];
    char* ws = (char*)d_ws;
    double* acc     = (double*)ws;
    int* counts     = (int*)(ws + 64);
    int* plan       = (int*)(ws + 1024);
    ull* thrKey     = (ull*)(ws + 4096);
    float* pos_sum  = (float*)(ws + 8192);
    float* posnorm  = (float*)(ws + 16384);
    float* cert     = (float*)(ws + 32768);
    float2* part    = (float2*)(ws + 1048576);
    float* out      = (float*)d_out;

    hipMemsetAsync(ws, 0, 16384, stream);
    k_hist  <<<512, 256, 0, stream>>>(predict, counts);
    k_plan  <<<1,   256, 0, stream>>>(counts, plan);
    size_t need8 = 1048576 + (size_t)8 * BB * NPIX * sizeof(float2);
    size_t need4 = 1048576 + (size_t)4 * BB * NPIX * sizeof(float2);
    if (ws_size >= need8) {
        k_cert1<8> <<<BB * 16 * 8, 256, 0, stream>>>(feats, part);
        k_cert2<8> <<<512, 256, 0, stream>>>(part, cert);
    } else if (ws_size >= need4) {
        k_cert1<4> <<<BB * 16 * 4, 256, 0, stream>>>(feats, part);
        k_cert2<4> <<<512, 256, 0, stream>>>(part, cert);
    } else {
        k_cert_direct <<<128, 256, 0, stream>>>(feats, cert);
    }
    k_sel   <<<128, 512, 0, stream>>>(predict, cert, plan, thrKey);
    k_accum <<<256, 512, 0, stream>>>(feats, predict, cert, plan, thrKey, pos_sum);
    k_intra <<<1,   256, 0, stream>>>(plan, pos_sum, posnorm, acc);
    k_inter <<<512, 256, 0, stream>>>(feats, predict, plan, pos_sum, posnorm, acc);
    k_finish<<<1,   1,   0, stream>>>(acc, out);
}

// Round 5
// 273.246 us; speedup vs baseline: 1.7751x; 1.0250x over previous
//
#include <hip/hip_runtime.h>
#include <math.h>

#define BB 8
#define NCLS 16
#define NPIX 16384
#define CHN 256
#define MAXV 200
#define SORTN 2048

typedef unsigned long long ull;

// ---------------- ws layout (bytes) ----------------
// 0       : double acc
// 64      : int counts[128]
// 1024    : int plan[536]: [0]=n_view [1]=k [2]=P [3]=D,
//           chan[16]@+4, pimg[128]@+20, pcls[128]@+148, pmap[128]@+276, Lp[128]@+404
// 4096    : ull thrKey[128]
// 8192    : float pos_sum[2048]   (zeroed)
// 16384   : float posnorm[128]
// 32768   : float cert[131072]    (512 KB)
// 1048576 : float2 part[NC*8*16384]

__global__ __launch_bounds__(256) void k_hist(const int* __restrict__ predict,
                                              int* __restrict__ counts) {
    __shared__ int h[NCLS];
    int tid = threadIdx.x;
    if (tid < NCLS) h[tid] = 0;
    __syncthreads();
    int base = blockIdx.x * 256;
    int b = base >> 14;
    int v = predict[base + tid];
    if (v >= 0 && v < NCLS) atomicAdd(&h[v], 1);
    __syncthreads();
    if (tid < NCLS && h[tid] > 0) atomicAdd(&counts[b * NCLS + tid], h[tid]);
}

__global__ __launch_bounds__(256) void k_plan(const int* __restrict__ counts,
                                              int* __restrict__ plan) {
    __shared__ int c[128];
    __shared__ int sc[128];
    __shared__ int mn[128];
    __shared__ int present[NCLS];
    int tid = threadIdx.x;
    int* chan = plan + 4;
    int* pimg = plan + 20;
    int* pcls = plan + 148;
    int* pmap = plan + 276;
    int* Lp   = plan + 404;
    if (tid < 128) c[tid] = counts[tid];
    if (tid < NCLS) present[tid] = 0;
    __syncthreads();
    int e = 0;
    if (tid < 128) {
        if (c[tid] > 0) atomicOr(&present[tid & 15], 1);
        e = (c[tid] >= MAXV) ? 1 : 0;
        sc[tid] = e;
        mn[tid] = e ? c[tid] : 0x7fffffff;
    }
    __syncthreads();
    for (int off = 1; off < 128; off <<= 1) {
        int add = 0;
        if (tid < 128 && tid >= off) add = sc[tid - off];
        __syncthreads();
        if (tid < 128) sc[tid] += add;
        __syncthreads();
    }
    for (int s = 64; s > 0; s >>= 1) {
        if (tid < s) mn[tid] = min(mn[tid], mn[tid + s]);
        __syncthreads();
    }
    if (tid < 128) {
        pmap[tid] = e ? (sc[tid] - 1) : -1;
        if (e) {
            int p = sc[tid] - 1;
            pimg[p] = tid >> 4; pcls[p] = tid & 15; Lp[p] = c[tid];
        }
    }
    if (tid == 0) {
        int D = 0;
        for (int v = 0; v < NCLS; ++v) if (present[v]) chan[D++] = v;
        int nview = mn[0];
        plan[0] = nview; plan[1] = nview / 2; plan[2] = sc[127]; plan[3] = D;
    }
}

// phase 1: explicit 8-deep load batching (loads issued before ANY compare use)
template <int NC>
__global__ __launch_bounds__(256) void k_cert1(const float* __restrict__ feats,
                                               float2* __restrict__ part) {
    int bid = blockIdx.x;                  // BB * 16 * NC blocks
    int chunk = bid % NC;
    int tile  = (bid / NC) % 16;
    int b     = bid / (NC * 16);
    int n4 = tile * 1024 + threadIdx.x * 4;
    const float* fb = feats + (size_t)b * CHN * NPIX + n4;
    int c0 = chunk * (CHN / NC);
    float m1[4] = {-INFINITY, -INFINITY, -INFINITY, -INFINITY};
    float m2[4] = {-INFINITY, -INFINITY, -INFINITY, -INFINITY};
    for (int cb = c0; cb < c0 + CHN / NC; cb += 8) {
        float4 xs[8];
#pragma unroll
        for (int u = 0; u < 8; ++u)
            xs[u] = *(const float4*)(fb + (size_t)(cb + u) * NPIX);
#pragma unroll
        for (int u = 0; u < 8; ++u) {
            float xv[4] = {xs[u].x, xs[u].y, xs[u].z, xs[u].w};
#pragma unroll
            for (int q = 0; q < 4; ++q) {
                float val = xv[q];
                if (val > m1[q]) { m2[q] = m1[q]; m1[q] = val; }
                else if (val > m2[q]) m2[q] = val;
            }
        }
    }
    float2* po = part + (((size_t)(b * NC + chunk)) << 14) + n4;
#pragma unroll
    for (int q = 0; q < 4; ++q) po[q] = make_float2(m1[q], m2[q]);
}

template <int NC>
__global__ __launch_bounds__(256) void k_cert2(const float2* __restrict__ part,
                                               float* __restrict__ cert) {
    int t = blockIdx.x * 256 + threadIdx.x;
    int b = t >> 14, pix = t & (NPIX - 1);
    float2 pm[NC];
#pragma unroll
    for (int j = 0; j < NC; ++j)
        pm[j] = part[(((size_t)(b * NC + j)) << 14) + pix];
    float m1 = -INFINITY, m2 = -INFINITY;
#pragma unroll
    for (int j = 0; j < NC; ++j) {
        if (pm[j].x > m1) { m2 = fmaxf(m1, pm[j].y); m1 = pm[j].x; }
        else              { m2 = fmaxf(m2, pm[j].x); }
    }
    cert[t] = m1 - m2;
}

// per-(b,v) radix-select the kv-th largest 64-bit key -> threshold
__global__ __launch_bounds__(512) void k_sel(const int* __restrict__ predict,
                                             const float* __restrict__ cert,
                                             const int* __restrict__ plan,
                                             ull* __restrict__ thrKey) {
    __shared__ ull keys[SORTN];
    __shared__ int whist[8][256];
    __shared__ int scan[257];
    __shared__ int wtot[4];
    __shared__ int lcnt;
    __shared__ ull sprefix;
    __shared__ int sremain;
    __shared__ int sdone;
    int tid = threadIdx.x;
    int lane = tid & 63, wv = tid >> 6;
    int b = blockIdx.x >> 4, v = blockIdx.x & 15;
    const int* pmap = plan + 276;
    int p = pmap[b * NCLS + v];
    if (p < 0) return;
    if (tid == 0) { lcnt = 0; sprefix = 0; sdone = 0; }
    __syncthreads();
    for (int n = tid; n < NPIX; n += 512) {
        bool match = (predict[b * NPIX + n] == v);
        ull mask = __ballot(match);
        if (mask) {
            int leader = __ffsll((long long)mask) - 1;
            int basepos = 0;
            if (lane == leader) basepos = atomicAdd(&lcnt, __popcll(mask));
            basepos = __shfl(basepos, leader, 64);
            if (match) {
                int pos = basepos + __popcll(mask & ((1ull << lane) - 1));
                if (pos < SORTN) {
                    unsigned int m = __float_as_uint(cert[b * NPIX + n]) | 0x80000000u;
                    keys[pos] = ((ull)m << 32) | (ull)(0xFFFFFFFFu - (unsigned)n);
                }
            }
        }
    }
    __syncthreads();
    int L = lcnt < SORTN ? lcnt : SORTN;
    int kv = plan[1] < L ? plan[1] : L;
    if (tid == 0) sremain = kv;
    __syncthreads();
    for (int shift = 56; shift >= 0; shift -= 8) {
        if (sdone) break;
        for (int i = tid; i < 8 * 256; i += 512) ((int*)whist)[i] = 0;
        ull pref = sprefix;
        int rem = sremain;
        __syncthreads();
        ull maskHi = (shift == 56) ? 0ULL : (~0ULL) << (shift + 8);
        for (int i = tid; i < L; i += 512) {
            ull kk = keys[i];
            if ((kk & maskHi) == pref)
                atomicAdd(&whist[wv][(int)((kk >> shift) & 255)], 1);
        }
        __syncthreads();
        int s = 0;
        if (tid < 256) {
            for (int w = 0; w < 8; ++w) s += whist[w][tid];
            for (int off = 1; off < 64; off <<= 1) {
                int o = __shfl_down(s, off, 64);
                if (lane + off < 64) s += o;
            }
            if (lane == 0) wtot[wv] = s;
        }
        __syncthreads();
        if (tid < 256) {
            int offs = 0;
            for (int w2 = wv + 1; w2 < 4; ++w2) offs += wtot[w2];
            s += offs;
            scan[tid] = s;
            if (tid == 0) scan[256] = 0;
        }
        __syncthreads();
        if (tid < 256) {
            int nxt = scan[tid + 1];
            if (s >= rem && nxt < rem) {
                sprefix = pref | ((ull)tid << shift);
                sremain = rem - nxt;
                if (s == rem) sdone = 1;
            }
        }
        __syncthreads();
    }
    if (tid == 0) thrKey[p] = sprefix;
}

// coalesced sweep accumulation; pos_sum is the UNNORMALIZED mean (cosines are
// scale-invariant). D==16 fast path batches the 16 plane loads.
__global__ __launch_bounds__(512) void k_accum(const float* __restrict__ feats,
                                               const int* __restrict__ predict,
                                               const float* __restrict__ cert,
                                               const int* __restrict__ plan,
                                               const ull* __restrict__ thrKey,
                                               float* __restrict__ pos_sum) {
    __shared__ float gacc[NCLS * 16];
    int tid = threadIdx.x;
    int t = blockIdx.x * 512 + tid;
    int b = (blockIdx.x * 512) >> 14;
    int n = t & (NPIX - 1);
    const int* chan = plan + 4;
    const int* pmap = plan + 276;
    int D = plan[3];
    if (tid < NCLS * 16) gacc[tid] = 0.f;
    __syncthreads();
    int v = predict[t];
    if (v >= 0 && v < NCLS) {
        int p = pmap[b * NCLS + v];
        if (p >= 0) {
            unsigned int m = __float_as_uint(cert[t]) | 0x80000000u;
            ull key = ((ull)m << 32) | (ull)(0xFFFFFFFFu - (unsigned)n);
            if (key >= thrKey[p]) {
                const float* fb = feats + ((size_t)(b * CHN) << 14) + n;
                if (D == 16) {
                    float x[16];
#pragma unroll
                    for (int d = 0; d < 16; ++d)
                        x[d] = fb[(size_t)chan[d] << 14];
#pragma unroll
                    for (int d = 0; d < 16; ++d)
                        atomicAdd(&gacc[v * 16 + d], x[d]);
                } else {
                    for (int d = 0; d < D; ++d)
                        atomicAdd(&gacc[v * 16 + d], fb[(size_t)chan[d] << 14]);
                }
            }
        }
    }
    __syncthreads();
    if (tid < NCLS * 16) {
        int p = pmap[b * NCLS + (tid >> 4)];
        if (p >= 0 && gacc[tid] != 0.f) atomicAdd(&pos_sum[p * 16 + (tid & 15)], gacc[tid]);
    }
}

__global__ __launch_bounds__(256) void k_intra(const int* __restrict__ plan,
                                               const float* __restrict__ pos_,
                                               float* __restrict__ posnorm,
                                               double* __restrict__ acc) {
    __shared__ float ppd[128 * 16];
    __shared__ float nr[128];
    __shared__ int cl[128];
    __shared__ double red[256];
    int tid = threadIdx.x;
    int P = plan[2], D = plan[3];
    const int* pcls = plan + 148;
    for (int i = tid; i < P * 16; i += 256) ppd[i] = pos_[i];
    __syncthreads();
    for (int p = tid; p < P; p += 256) {
        float s = 0;
        for (int d = 0; d < D; ++d) { float x = ppd[p * 16 + d]; s += x * x; }
        float nn = sqrtf(s);
        nr[p] = nn; posnorm[p] = nn; cl[p] = pcls[p];
    }
    __syncthreads();
    double num = 0; int cnt = 0;
    for (int idx = tid; idx < P * P; idx += 256) {
        int i = idx / P, j = idx - i * P;
        if (cl[i] != cl[j]) {
            float dot = 0;
            for (int d = 0; d < D; ++d) dot += ppd[i * 16 + d] * ppd[j * 16 + d];
            num += (double)(dot / (nr[i] * nr[j])) + 1.0;
            cnt++;
        }
    }
    red[tid] = num; __syncthreads();
    for (int s = 128; s > 0; s >>= 1) { if (tid < s) red[tid] += red[tid + s]; __syncthreads(); }
    double totnum = red[0]; __syncthreads();
    red[tid] = (double)cnt; __syncthreads();
    for (int s = 128; s > 0; s >>= 1) { if (tid < s) red[tid] += red[tid + s]; __syncthreads(); }
    if (tid == 0) atomicAdd(acc, totnum / red[0]);
}

__global__ __launch_bounds__(256) void k_inter(const float* __restrict__ feats,
                                               const int* __restrict__ predict,
                                               const int* __restrict__ plan,
                                               const float* __restrict__ pos_,
                                               const float* __restrict__ posnorm,
                                               double* __restrict__ acc) {
    __shared__ double red[256];
    int tid = threadIdx.x;
    int t = blockIdx.x * 256 + tid;
    int b = t >> 14, n = t & (NPIX - 1);
    int P = plan[2], D = plan[3];
    const int* chan = plan + 4;
    const int* pmap = plan + 276;
    const int* Lp = plan + 404;
    double term = 0;
    int v = predict[t];
    if (v >= 0 && v < NCLS) {
        int p = pmap[b * NCLS + v];
        if (p >= 0) {
            const float* fb = feats + ((size_t)(b * CHN) << 14) + n;
            float dot = 0, nv = 0;
            if (D == 16) {
                float x[16];
#pragma unroll
                for (int d = 0; d < 16; ++d) x[d] = fb[(size_t)chan[d] << 14];
#pragma unroll
                for (int d = 0; d < 16; ++d) {
                    float y = pos_[p * 16 + d];
                    dot += x[d] * y; nv += x[d] * x[d];
                }
            } else {
                for (int d = 0; d < D; ++d) {
                    float x = fb[(size_t)chan[d] << 14];
                    float y = pos_[p * 16 + d];
                    dot += x * y; nv += x * x;
                }
            }
            float den = fmaxf(sqrtf(nv) * posnorm[p], 1e-8f);
            term = (1.0 - (double)(dot / den)) / ((double)Lp[p] * (double)P);
        }
    }
    red[tid] = term; __syncthreads();
    for (int s = 128; s > 0; s >>= 1) { if (tid < s) red[tid] += red[tid + s]; __syncthreads(); }
    if (tid == 0) atomicAdd(acc, red[0]);
}

__global__ void k_finish(const double* __restrict__ acc, float* __restrict__ out) {
    out[0] = (float)acc[0];
}

// fallback single-phase cert (only if ws is too small for partials)
__global__ __launch_bounds__(256) void k_cert_direct(const float* __restrict__ feats,
                                                     float* __restrict__ cert) {
    int t = blockIdx.x * 256 + threadIdx.x;
    int b = t >> 12;
    int n4 = (t & 4095) * 4;
    const float* fb = feats + (size_t)b * CHN * NPIX + n4;
    float m1[4] = {-INFINITY, -INFINITY, -INFINITY, -INFINITY};
    float m2[4] = {-INFINITY, -INFINITY, -INFINITY, -INFINITY};
    for (int cb = 0; cb < CHN; cb += 8) {
        float4 xs[8];
#pragma unroll
        for (int u = 0; u < 8; ++u)
            xs[u] = *(const float4*)(fb + (size_t)(cb + u) * NPIX);
#pragma unroll
        for (int u = 0; u < 8; ++u) {
            float xv[4] = {xs[u].x, xs[u].y, xs[u].z, xs[u].w};
#pragma unroll
            for (int q = 0; q < 4; ++q) {
                float val = xv[q];
                if (val > m1[q]) { m2[q] = m1[q]; m1[q] = val; }
                else if (val > m2[q]) m2[q] = val;
            }
        }
    }
    float4 o = {m1[0] - m2[0], m1[1] - m2[1], m1[2] - m2[2], m1[3] - m2[3]};
    *(float4*)(cert + b * NPIX + n4) = o;
}

extern "C" void kernel_launch(void* const* d_in, const int* in_sizes, int n_in,
                              void* d_out, int out_size, void* d_ws, size_t ws_size,
                              hipStream_t stream) {
    const float* feats  = (const float*)d_in[0];
    const int* predict  = (const int*)d_in[2];
    char* ws = (char*)d_ws;
    double* acc     = (double*)ws;
    int* counts     = (int*)(ws + 64);
    int* plan       = (int*)(ws + 1024);
    ull* thrKey     = (ull*)(ws + 4096);
    float* pos_sum  = (float*)(ws + 8192);
    float* posnorm  = (float*)(ws + 16384);
    float* cert     = (float*)(ws + 32768);
    float2* part    = (float2*)(ws + 1048576);
    float* out      = (float*)d_out;

    hipMemsetAsync(ws, 0, 16384, stream);
    k_hist  <<<512, 256, 0, stream>>>(predict, counts);
    k_plan  <<<1,   256, 0, stream>>>(counts, plan);
    size_t need8 = 1048576 + (size_t)8 * BB * NPIX * sizeof(float2);
    size_t need4 = 1048576 + (size_t)4 * BB * NPIX * sizeof(float2);
    if (ws_size >= need8) {
        k_cert1<8> <<<BB * 16 * 8, 256, 0, stream>>>(feats, part);
        k_cert2<8> <<<512, 256, 0, stream>>>(part, cert);
    } else if (ws_size >= need4) {
        k_cert1<4> <<<BB * 16 * 4, 256, 0, stream>>>(feats, part);
        k_cert2<4> <<<512, 256, 0, stream>>>(part, cert);
    } else {
        k_cert_direct <<<128, 256, 0, stream>>>(feats, cert);
    }
    k_sel   <<<128, 512, 0, stream>>>(predict, cert, plan, thrKey);
    k_accum <<<256, 512, 0, stream>>>(feats, predict, cert, plan, thrKey, pos_sum);
    k_intra <<<1,   256, 0, stream>>>(plan, pos_sum, posnorm, acc);
    k_inter <<<512, 256, 0, stream>>>(feats, predict, plan, pos_sum, posnorm, acc);
    k_finish<<<1,   1,   0, stream>>>(acc, out);
}